// Round 1
// baseline (218.634 us; speedup 1.0000x reference)
//
#include <hip/hip_runtime.h>
#include <stdint.h>
#include <stddef.h>

#define DIM 1024
#define EPS 1e-8f

typedef __attribute__((ext_vector_type(4)))  int   i32x4;
typedef __attribute__((ext_vector_type(8)))  int   i32x8;
typedef __attribute__((ext_vector_type(16))) float f32x16;

// e8m0 scale byte 123 = 2^(123-127) = 1/16 per operand -> 1/256 on the product,
// exactly cancelling the x16 prep scaling (bit-exact: pow2 exponent shift).
#define SCALE8 0x7B7B7B7B

// async global->LDS, 16B per lane, wave-uniform LDS base + lane*16
__device__ __forceinline__ void async_copy16(const void* g, void* l) {
    __builtin_amdgcn_global_load_lds(
        (__attribute__((address_space(1))) void*)const_cast<void*>(g),
        (__attribute__((address_space(3))) void*)(l), 16, 0, 0);
}

// drain all but newest N vmem ops, then barrier
#define PIPE_SYNC(N) asm volatile("s_waitcnt vmcnt(" #N ")\n\ts_barrier" ::: "memory")

// ---------------------------------------------------------------------------
// Prep: wave-per-row. Unit-normalize, scale by 16 (undone by hw e8m0 scales in
// the GEMM), cast to OCP fp8 e4m3. Rows now stored LINEARLY (k ascending) —
// the MX 32x32x64 fragment wants 32 contiguous k-bytes per lane; the GEMM's
// staging-side chunk XOR supplies the bank swizzle. Stores are fully
// coalesced 4-B dwords (lane-contiguous per store instruction).
// ---------------------------------------------------------------------------
__global__ __launch_bounds__(256)
void prep_all(const float* __restrict__ x, const float* __restrict__ pos,
              const float* __restrict__ neg,
              unsigned char* __restrict__ Xn, unsigned char* __restrict__ Nn,
              float* __restrict__ simOut, float* __restrict__ rowsum, int bn) {
    const int lane = threadIdx.x & 63;
    const int wave = threadIdx.x >> 6;
    const int grow = blockIdx.x * 4 + wave;
    const bool isX = grow < bn;
    const int row  = isX ? grow : grow - bn;
    const float* src = isX ? x : neg;
    unsigned char* dst = isX ? Xn : Nn;

    const float4* s = (const float4*)(src + (size_t)row * DIM);
    float4 xv[4], pv[4];
    float sxx = 0.f, spp = 0.f, sxp = 0.f;
#pragma unroll
    for (int i = 0; i < 4; i++) {
        xv[i] = s[lane + 64 * i];
        sxx += xv[i].x * xv[i].x + xv[i].y * xv[i].y + xv[i].z * xv[i].z + xv[i].w * xv[i].w;
    }
    if (isX) {
        const float4* p = (const float4*)(pos + (size_t)row * DIM);
#pragma unroll
        for (int i = 0; i < 4; i++) {
            pv[i] = p[lane + 64 * i];
            spp += pv[i].x * pv[i].x + pv[i].y * pv[i].y + pv[i].z * pv[i].z + pv[i].w * pv[i].w;
            sxp += xv[i].x * pv[i].x + xv[i].y * pv[i].y + xv[i].z * pv[i].z + xv[i].w * pv[i].w;
        }
#pragma unroll
        for (int off = 1; off < 64; off <<= 1) {
            sxx += __shfl_xor(sxx, off);
            spp += __shfl_xor(spp, off);
            sxp += __shfl_xor(sxp, off);
        }
    } else {
#pragma unroll
        for (int off = 1; off < 64; off <<= 1) sxx += __shfl_xor(sxx, off);
    }
    const float nx  = sqrtf(sxx);
    const float inv = (nx > 0.f) ? (16.f / nx) : 0.f;   // x16 -> e4m3 sweet spot
    if (isX && lane == 0) {
        const float np = sqrtf(spp);
        simOut[row] = sxp / fmaxf(nx * np, EPS);
        rowsum[row] = 0.f;
    }
    unsigned int t;
    t = __builtin_amdgcn_cvt_pk_fp8_f32(xv[0].x * inv, xv[0].y * inv, 0, false);
    unsigned int q0 = __builtin_amdgcn_cvt_pk_fp8_f32(xv[0].z * inv, xv[0].w * inv, t, true);
    t = __builtin_amdgcn_cvt_pk_fp8_f32(xv[1].x * inv, xv[1].y * inv, 0, false);
    unsigned int q1 = __builtin_amdgcn_cvt_pk_fp8_f32(xv[1].z * inv, xv[1].w * inv, t, true);
    t = __builtin_amdgcn_cvt_pk_fp8_f32(xv[2].x * inv, xv[2].y * inv, 0, false);
    unsigned int q2 = __builtin_amdgcn_cvt_pk_fp8_f32(xv[2].z * inv, xv[2].w * inv, t, true);
    t = __builtin_amdgcn_cvt_pk_fp8_f32(xv[3].x * inv, xv[3].y * inv, 0, false);
    unsigned int q3 = __builtin_amdgcn_cvt_pk_fp8_f32(xv[3].z * inv, xv[3].w * inv, t, true);

    // q_i holds floats [4*(lane+64i), 4*(lane+64i)+4) -> dword index lane+64i.
    unsigned int* wr = (unsigned int*)(dst + (size_t)row * DIM);
    wr[lane]       = q0;
    wr[lane + 64]  = q1;
    wr[lane + 128] = q2;
    wr[lane + 192] = q3;
}

// ---------------------------------------------------------------------------
// Fused MX-fp8 GEMM: rowsum[i] += sum_j exp( unit(x_i) . unit(neg_j) )
// 128x128 tile, BK=64 B per stage, 3-stage LDS (48 KB), prefetch distance 2
// via s_waitcnt vmcnt(4)+s_barrier (verified skeleton, unchanged).
// Per stage per wave: 8 ds_read_b128 + 4 x mfma_scale_f32_32x32x64_f8f6f4
// (2x the pipe rate of the old 32 x 16x16x32 fp8 MFMAs, same FLOPs).
// Fragment: lane = row(l&31), k-half kh=(l>>5); 32 contiguous k-bytes as
// 2 b128 at chunk slots ((2kh+i) ^ ((row>>1)&3)) — same row-XOR swizzle as
// the staging side, 2-way (free) bank aliasing per 16-lane phase group.
// HW e8m0 scales (0x7B = 2^-4 each side) undo the x16*x16 prep scaling.
// ---------------------------------------------------------------------------
__global__ __launch_bounds__(256, 3)
void gemm_exp_rowsum(const unsigned char* __restrict__ Xn,
                     const unsigned char* __restrict__ Nn,
                     float* __restrict__ rowsum) {
    constexpr int KB   = DIM;        // 1024 bytes per fp8 row
    constexpr int BK   = 64;         // bytes per stage-row (one k-window)
    constexpr int BUFB = 128 * BK;   // 8 KB per buffer
    __shared__ __align__(16) unsigned char Ash[3][BUFB];
    __shared__ __align__(16) unsigned char Bsh[3][BUFB];

    const int tid  = threadIdx.x;
    const int lane = tid & 63;
    const int wave = tid >> 6;
    const int rowBase = blockIdx.y * 128;
    const int colBase = blockIdx.x * 128;

    // staging: one glds = 1 KB = 16 rows x 64 B; lane -> (row, chunk).
    // LDS chunk slot p of row r receives global logical chunk p ^ ((r>>1)&3).
    const int srow   = lane >> 2;                       // 0..15
    const int schunk = (lane & 3) ^ ((srow >> 1) & 3);  // global-side swizzle
    const unsigned char* gA = Xn + (size_t)(rowBase + wave * 16 + srow) * KB + schunk * 16;
    const unsigned char* gB = Nn + (size_t)(colBase + wave * 16 + srow) * KB + schunk * 16;
    const int lgrp0 = (wave * 16) * BK;
    const int lgrp1 = (wave * 16 + 64) * BK;

    f32x16 acc[2][2];
#pragma unroll
    for (int mi = 0; mi < 2; mi++)
#pragma unroll
        for (int ni = 0; ni < 2; ni++)
#pragma unroll
            for (int e = 0; e < 16; e++) acc[mi][ni][e] = 0.f;

    const int m0   = (wave >> 1) * 64;
    const int n0   = (wave & 1) * 64;
    const int mrow = lane & 31;          // row within a 32-row fragment
    const int kh   = lane >> 5;          // k-half (bytes 32*kh .. +32 of window)
    const int kx   = (mrow >> 1) & 3;    // read-side swizzle key
    const int c0   = ((2 * kh + 0) ^ kx) << 4;
    const int c1   = ((2 * kh + 1) ^ kx) << 4;

    int arow[2], brow[2];
#pragma unroll
    for (int i = 0; i < 2; i++) {
        arow[i] = (m0 + 32 * i + mrow) * BK;
        brow[i] = (n0 + 32 * i + mrow) * BK;
    }

#define STAGE(buf, stg)                                                  \
    do {                                                                 \
        const int kq = (stg) * BK;                                       \
        async_copy16(gA + kq,            &Ash[buf][lgrp0]);              \
        async_copy16(gA + 64 * KB + kq,  &Ash[buf][lgrp1]);              \
        async_copy16(gB + kq,            &Bsh[buf][lgrp0]);              \
        async_copy16(gB + 64 * KB + kq,  &Bsh[buf][lgrp1]);              \
    } while (0)

#define COMPUTE(buf)                                                     \
    do {                                                                 \
        i32x8 Af[2], Bf[2];                                              \
        _Pragma("unroll")                                                \
        for (int i = 0; i < 2; i++) {                                    \
            i32x4 alo = *(const i32x4*)&Ash[buf][arow[i] + c0];          \
            i32x4 ahi = *(const i32x4*)&Ash[buf][arow[i] + c1];          \
            Af[i] = __builtin_shufflevector(alo, ahi, 0, 1, 2, 3, 4, 5, 6, 7); \
            i32x4 blo = *(const i32x4*)&Bsh[buf][brow[i] + c0];          \
            i32x4 bhi = *(const i32x4*)&Bsh[buf][brow[i] + c1];          \
            Bf[i] = __builtin_shufflevector(blo, bhi, 0, 1, 2, 3, 4, 5, 6, 7); \
        }                                                                \
        _Pragma("unroll")                                                \
        for (int mi = 0; mi < 2; mi++)                                   \
            _Pragma("unroll")                                            \
            for (int ni = 0; ni < 2; ni++)                               \
                acc[mi][ni] = __builtin_amdgcn_mfma_scale_f32_32x32x64_f8f6f4( \
                    Af[mi], Bf[ni], acc[mi][ni], 0, 0, 0, SCALE8, 0, SCALE8); \
    } while (0)

    STAGE(0, 0);
    STAGE(1, 1);
    // 16 stages; stage s computed at phase s in buffer s%3, staged 2 ahead
    for (int it = 0; it < 4; it++) {
        const int s = 3 * it + 2;
        PIPE_SYNC(4); STAGE(2, s);     COMPUTE(0);
        PIPE_SYNC(4); STAGE(0, s + 1); COMPUTE(1);
        PIPE_SYNC(4); STAGE(1, s + 2); COMPUTE(2);
    }
    PIPE_SYNC(4); STAGE(2, 14); COMPUTE(0);   // stage 12
    PIPE_SYNC(4); STAGE(0, 15); COMPUTE(1);   // stage 13
    PIPE_SYNC(4);               COMPUTE(2);   // stage 14
    PIPE_SYNC(0);               COMPUTE(0);   // stage 15
#undef STAGE
#undef COMPUTE

    // epilogue: acc already holds unit-vector dots (hw scales applied).
    // 32x32 C/D layout: col = lane&31, row = (reg&3) + 8*(reg>>2) + 4*kh.
    // Sum over ni (cols n0.. and n0+32..), exp, reduce across the 32 cols
    // held by each 32-lane half, one atomic per row per block.
#pragma unroll
    for (int mi = 0; mi < 2; mi++) {
        float rs[16];
#pragma unroll
        for (int r = 0; r < 16; r++) {
            float v = __expf(acc[mi][0][r]) + __expf(acc[mi][1][r]);
            v += __shfl_xor(v, 1);
            v += __shfl_xor(v, 2);
            v += __shfl_xor(v, 4);
            v += __shfl_xor(v, 8);
            v += __shfl_xor(v, 16);
            rs[r] = v;
        }
        if ((lane & 31) == 0) {
            const int rbase = rowBase + m0 + 32 * mi + 4 * kh;
#pragma unroll
            for (int r = 0; r < 16; r++)
                atomicAdd(&rowsum[rbase + (r & 3) + 8 * (r >> 2)], rs[r]);
        }
    }
}

__global__ __launch_bounds__(1024)
void loss_kernel(const float* __restrict__ rowsum, const float* __restrict__ sim,
                 float* __restrict__ out, int bn) {
    const int tid  = threadIdx.x;
    const int lane = tid & 63;
    const int wave = tid >> 6;
    float acc = 0.f;
    for (int i = tid; i < bn; i += 1024) acc += logf(rowsum[i]) - sim[i];
#pragma unroll
    for (int off = 1; off < 64; off <<= 1) acc += __shfl_xor(acc, off);
    __shared__ float red[16];
    if (lane == 0) red[wave] = acc;
    __syncthreads();
    if (tid == 0) {
        float t = 0.f;
#pragma unroll
        for (int i = 0; i < 16; i++) t += red[i];
        out[0] = t / (float)bn;
    }
}

extern "C" void kernel_launch(void* const* d_in, const int* in_sizes, int n_in,
                              void* d_out, int out_size, void* d_ws, size_t ws_size,
                              hipStream_t stream) {
    const float* x   = (const float*)d_in[0];
    const float* pos = (const float*)d_in[1];
    const float* neg = (const float*)d_in[2];
    const int bn = in_sizes[0] / DIM;  // 4096
    const int cn = in_sizes[2] / DIM;  // 8192

    // ws layout: Xn fp8 [bn*DIM] | Nn fp8 [cn*DIM] | sim f32 [bn] | rowsum f32 [bn]
    unsigned char* Xn = (unsigned char*)d_ws;
    unsigned char* Nn = Xn + (size_t)bn * DIM;
    float* sim    = (float*)(Nn + (size_t)cn * DIM);
    float* rowsum = sim + bn;

    prep_all<<<dim3((bn + cn) / 4), dim3(256), 0, stream>>>(x, pos, neg, Xn, Nn, sim, rowsum, bn);
    gemm_exp_rowsum<<<dim3(cn / 128, bn / 128), dim3(256), 0, stream>>>(Xn, Nn, rowsum);
    loss_kernel<<<dim3(1), dim3(1024), 0, stream>>>(rowsum, sim, (float*)d_out, bn);
}